// Round 7
// baseline (187.065 us; speedup 1.0000x reference)
//
#include <hip/hip_runtime.h>
#include <hip/hip_bf16.h>

// Sizes (fixed): b=2, n=1024, dim=512, h=8, L=8, dh=64
// exp(-d2/T) with T=0.1 -> exp2(C*d2), C = -10*log2(e)
#define CEXP (-14.4269504088896340736f)

typedef __attribute__((ext_vector_type(8))) short bfrag8;   // 8 bf16 (4 VGPR) MFMA operand
typedef __attribute__((ext_vector_type(4))) float fvec4;    // MFMA accumulator
typedef __attribute__((ext_vector_type(8))) unsigned short ushort8;

__device__ inline unsigned short f2bf(float f) {            // RNE float->bf16
    unsigned u = __builtin_bit_cast(unsigned, f);
    u += 0x7fffu + ((u >> 16) & 1u);
    return (unsigned short)(u >> 16);
}
__device__ inline float bf2f(unsigned short h) {
    unsigned u = ((unsigned)h) << 16;
    return __builtin_bit_cast(float, u);
}

// Wave64 sum via DPP (rocPRIM pattern). ctrl/rmask must be immediates -> template params.
template <int CTRL, int RMASK>
__device__ __forceinline__ float dpp_add(float v) {
    int m = __builtin_amdgcn_update_dpp(0, __builtin_bit_cast(int, v), CTRL, RMASK, 0xf, true);
    return v + __builtin_bit_cast(float, m);
}
__device__ __forceinline__ float wave_sum64(float v) {
    v = dpp_add<0xB1,  0xf>(v);   // quad_perm(1,0,3,2)
    v = dpp_add<0x4E,  0xf>(v);   // quad_perm(2,3,0,1)
    v = dpp_add<0x141, 0xf>(v);   // row_half_mirror
    v = dpp_add<0x140, 0xf>(v);   // row_mirror -> each row-of-16 has its sum
    v = dpp_add<0x142, 0xa>(v);   // row_bcast15 into rows 1,3
    v = dpp_add<0x143, 0xc>(v);   // row_bcast31 into rows 2,3
    return __builtin_bit_cast(float, __builtin_amdgcn_readlane(__builtin_bit_cast(int, v), 63));
}

// ---------------- K_B: Wqp[c][hl] = sum_d Wq[c][h*64+d]*th_hat[h][l][d] ----------
__global__ __launch_bounds__(256) void k_wproj(const float* __restrict__ Wqkv,
                                               const float* __restrict__ theta,
                                               float* __restrict__ Wqp,
                                               float* __restrict__ Wkp) {
    __shared__ float th_s[64 * 65];
    int tid = threadIdx.x;
    int hl = tid & 63, cl = tid >> 6;
    #pragma unroll
    for (int i = 0; i < 16; ++i) {
        int r = cl * 16 + i;
        th_s[r * 65 + hl] = theta[r * 64 + hl];
    }
    __syncthreads();
    const float* ts = th_s + hl * 65;
    float ss = 0.f;
    #pragma unroll 8
    for (int d = 0; d < 64; ++d) ss = fmaf(ts[d], ts[d], ss);
    float inv = rsqrtf(ss);
    int c = blockIdx.x * 4 + cl;
    int h = hl >> 3;
    const float* wq = Wqkv + c * 1536 + h * 64;
    const float* wk = wq + 512;
    float aq = 0.f, ak = 0.f;
    #pragma unroll 4
    for (int d = 0; d < 64; ++d) {
        float tv = ts[d];
        aq = fmaf(wq[d], tv, aq);
        ak = fmaf(wk[d], tv, ak);
    }
    Wqp[c * 64 + hl] = aq * inv;
    Wkp[c * 64 + hl] = ak * inv;
}

// ---------------- K_C: qp/kp = scale * x @ W{q,k}p, layout [bh][l][n] ----------------
// 512 blocks x 4 rows; thread = (q|k, hl) x 2 rows.
__global__ __launch_bounds__(256) void k_qkp(const float* __restrict__ x,
                                             const float* __restrict__ Wqp,
                                             const float* __restrict__ Wkp,
                                             float* __restrict__ qp,
                                             float* __restrict__ kp) {
    __shared__ float xs[4 * 512];            // 8 KB
    int tid = threadIdx.x;
    int i0 = blockIdx.x * 4;                 // 512 blocks
    const float4* xg = (const float4*)(x + i0 * 512);
    float4* xs4 = (float4*)xs;
    #pragma unroll
    for (int j = 0; j < 2; ++j) xs4[j * 256 + tid] = xg[j * 256 + tid];
    __syncthreads();

    int t  = tid & 127;
    int rg = tid >> 7;                       // 0/1 -> rows rg*2, rg*2+1
    int hl = t & 63;
    const float* Bm = (t & 64) ? Wkp : Wqp;
    const float* xr = xs + rg * 2 * 512;
    float a[2] = {0.f, 0.f};
    for (int c4 = 0; c4 < 128; ++c4) {
        float b0 = Bm[(c4 * 4 + 0) * 64 + hl];
        float b1 = Bm[(c4 * 4 + 1) * 64 + hl];
        float b2 = Bm[(c4 * 4 + 2) * 64 + hl];
        float b3 = Bm[(c4 * 4 + 3) * 64 + hl];
        #pragma unroll
        for (int r = 0; r < 2; ++r) {
            float4 xv = *(const float4*)(xr + r * 512 + c4 * 4);
            a[r] = fmaf(xv.x, b0, fmaf(xv.y, b1, fmaf(xv.z, b2, fmaf(xv.w, b3, a[r]))));
        }
    }
    int h = hl >> 3, l = hl & 7;
    float* dst = (t & 64) ? kp : qp;
    #pragma unroll
    for (int r = 0; r < 2; ++r) {
        int row = i0 + rg * 2 + r;
        int b = row >> 10, i = row & 1023;
        dst[((b * 8 + h) * 8 + l) * 1024 + i] = a[r] * 0.125f;
    }
}

// ---------------- K_D: vT = (x @ Wv)^T as bf16 hi/lo, layout [bh][d][n] ----------------
// k_out clone: 256 blocks, 8 LDS rows, thread = 2 cols x 8 rows; packed ushort8 stores.
__global__ __launch_bounds__(256) void k_vproj(const float* __restrict__ x,
                                               const float* __restrict__ Wqkv,
                                               unsigned short* __restrict__ vThi,
                                               unsigned short* __restrict__ vTlo) {
    __shared__ float xs[8 * 512];            // 16 KB
    int tid = threadIdx.x;
    int i0 = blockIdx.x * 8;                 // 256 blocks
    const float4* xg = (const float4*)(x + i0 * 512);
    float4* xs4 = (float4*)xs;
    #pragma unroll
    for (int j = 0; j < 4; ++j) xs4[j * 256 + tid] = xg[j * 256 + tid];
    __syncthreads();

    float a0[8], a1[8];
    #pragma unroll
    for (int r = 0; r < 8; ++r) { a0[r] = 0.f; a1[r] = 0.f; }
    const float* wp0 = Wqkv + 1024 + tid;
    const float* wp1 = wp0 + 256;
    for (int c4 = 0; c4 < 128; ++c4) {
        float w00 = wp0[(c4 * 4 + 0) * 1536];
        float w01 = wp0[(c4 * 4 + 1) * 1536];
        float w02 = wp0[(c4 * 4 + 2) * 1536];
        float w03 = wp0[(c4 * 4 + 3) * 1536];
        float w10 = wp1[(c4 * 4 + 0) * 1536];
        float w11 = wp1[(c4 * 4 + 1) * 1536];
        float w12 = wp1[(c4 * 4 + 2) * 1536];
        float w13 = wp1[(c4 * 4 + 3) * 1536];
        #pragma unroll
        for (int r = 0; r < 8; ++r) {
            float4 xv = *(const float4*)(xs + r * 512 + c4 * 4);
            a0[r] = fmaf(xv.x, w00, fmaf(xv.y, w01, fmaf(xv.z, w02, fmaf(xv.w, w03, a0[r]))));
            a1[r] = fmaf(xv.x, w10, fmaf(xv.y, w11, fmaf(xv.z, w12, fmaf(xv.w, w13, a1[r]))));
        }
    }
    int b = i0 >> 10, ib = i0 & 1023;
    #pragma unroll
    for (int cc = 0; cc < 2; ++cc) {
        int col = cc * 256 + tid;
        int h = col >> 6, d = col & 63;
        float* ac = cc ? a1 : a0;
        ushort8 vh, vl;
        #pragma unroll
        for (int r = 0; r < 8; ++r) {
            unsigned short hi = f2bf(ac[r]);
            vh[r] = hi;
            vl[r] = f2bf(ac[r] - bf2f(hi));
        }
        size_t off = (size_t)(b * 8 + h) * 65536 + (size_t)d * 1024 + ib;
        *(ushort8*)(vThi + off) = vh;
        *(ushort8*)(vTlo + off) = vl;
    }
}

// ---------------- K_E: fused attention rows + MFMA PV ----------------
__global__ __launch_bounds__(256) void k_attn_pv(const float* __restrict__ qp,
                                                 const float* __restrict__ kp,
                                                 const unsigned short* __restrict__ vThi,
                                                 const unsigned short* __restrict__ vTlo,
                                                 float* __restrict__ attn,
                                                 float* __restrict__ oh) {
    __shared__ float s_buf[8 * 1024];        // 32 KB: kp (f32) phase 1; P hi/lo (bf16 [16][1024]) phase 2
    int bx = blockIdx.x;                     // 2048
    int bh = bx >> 7;
    int rowbase = (bx & 127) * 8;
    int tid = threadIdx.x;
    int w = tid >> 6, lane = tid & 63;

    const float4* kp4 = (const float4*)(kp + bh * 8192);
    float4* kps4 = (float4*)s_buf;
    #pragma unroll
    for (int k = 0; k < 8; ++k) kps4[k * 256 + tid] = kp4[k * 256 + tid];

    int rA = rowbase + 2 * w;
    int rB = rA + 1;
    float qA[8], qB[8];
    #pragma unroll
    for (int l = 0; l < 8; ++l) {
        qA[l] = qp[bh * 8192 + l * 1024 + rA];
        qB[l] = qp[bh * 8192 + l * 1024 + rB];
    }
    __syncthreads();

    float accA[16], accB[16];
    #pragma unroll
    for (int m = 0; m < 16; ++m) { accA[m] = 0.f; accB[m] = 0.f; }

    for (int l = 0; l < 8; ++l) {
        float kv[16], kv2[16];
        #pragma unroll
        for (int m = 0; m < 16; ++m) {
            kv[m] = s_buf[l * 1024 + m * 64 + lane];
            kv2[m] = CEXP * kv[m] * kv[m];       // C*k^2
        }
        float e[16];
        // ---- row A ----
        {
            float sq = -2.f * CEXP * qA[l];
            #pragma unroll
            for (int m = 0; m < 16; ++m) e[m] = __builtin_amdgcn_exp2f(fmaf(sq, kv[m], kv2[m]));
            float s = (((e[0]+e[1])+(e[2]+e[3])) + ((e[4]+e[5])+(e[6]+e[7])))
                    + (((e[8]+e[9])+(e[10]+e[11])) + ((e[12]+e[13])+(e[14]+e[15])));
            float inv = 0.125f * __builtin_amdgcn_rcpf(wave_sum64(s));
            #pragma unroll
            for (int m = 0; m < 16; ++m) accA[m] = fmaf(e[m], inv, accA[m]);
        }
        // ---- row B ----
        {
            float sq = -2.f * CEXP * qB[l];
            #pragma unroll
            for (int m = 0; m < 16; ++m) e[m] = __builtin_amdgcn_exp2f(fmaf(sq, kv[m], kv2[m]));
            float s = (((e[0]+e[1])+(e[2]+e[3])) + ((e[4]+e[5])+(e[6]+e[7])))
                    + (((e[8]+e[9])+(e[10]+e[11])) + ((e[12]+e[13])+(e[14]+e[15])));
            float inv = 0.125f * __builtin_amdgcn_rcpf(wave_sum64(s));
            #pragma unroll
            for (int m = 0; m < 16; ++m) accB[m] = fmaf(e[m], inv, accB[m]);
        }
    }

    float* aA = attn + ((size_t)(bh * 1024 + rA)) * 1024 + lane;
    float* aB = attn + ((size_t)(bh * 1024 + rB)) * 1024 + lane;
    #pragma unroll
    for (int m = 0; m < 16; ++m) { aA[m * 64] = accA[m]; aB[m * 64] = accB[m]; }

    __syncthreads();   // all waves done reading kp from s_buf

    // stash P as bf16 hi (rows 0-7) / lo (rows 8-15), XOR-swizzled: idx = r*1024 + (j ^ ((r&7)<<3))
    unsigned short* ps = (unsigned short*)s_buf;
    int lrA = 2 * w, lrB = lrA + 1;
    int swzA = lrA << 3, swzB = lrB << 3;
    #pragma unroll
    for (int m = 0; m < 16; ++m) {
        int j = m * 64 + lane;
        unsigned short hA = f2bf(accA[m]);
        unsigned short hB = f2bf(accB[m]);
        ps[lrA * 1024 + (j ^ swzA)]       = hA;
        ps[lrB * 1024 + (j ^ swzB)]       = hB;
        ps[(lrA + 8) * 1024 + (j ^ swzA)] = f2bf(accA[m] - bf2f(hA));
        ps[(lrB + 8) * 1024 + (j ^ swzB)] = f2bf(accB[m] - bf2f(hB));
    }
    __syncthreads();

    // Phase 2: wave w computes oh cols n0..n0+15 over full K=1024 via mfma 16x16x32.
    int n0 = w * 16;
    int ar  = lane & 15;
    int asw = (ar & 7) << 3;
    int ak  = (lane >> 4) * 8;
    const unsigned short* ap = ps + ar * 1024;
    size_t boff = (size_t)bh * 65536 + (size_t)(n0 + (lane & 15)) * 1024 + ak;
    const unsigned short* bh_p = vThi + boff;
    const unsigned short* bl_p = vTlo + boff;
    fvec4 acc = {0.f, 0.f, 0.f, 0.f};
    #pragma unroll 4
    for (int s = 0; s < 32; ++s) {
        bfrag8 a  = *(const bfrag8*)(ap + ((s * 32 + ak) ^ asw));
        bfrag8 vh = *(const bfrag8*)(bh_p + s * 32);
        bfrag8 vl = *(const bfrag8*)(bl_p + s * 32);
        acc = __builtin_amdgcn_mfma_f32_16x16x32_bf16(a, vh, acc, 0, 0, 0);
        acc = __builtin_amdgcn_mfma_f32_16x16x32_bf16(a, vl, acc, 0, 0, 0);
    }
    int b = bh >> 3, h = bh & 7;
    #pragma unroll
    for (int q = 0; q < 4; ++q) {
        float t = acc[q] + __shfl_xor(acc[q], 32);   // C[r] + C[r+8]
        if (lane < 32) {
            int row = rowbase + (lane >> 4) * 4 + q;
            oh[(b * 1024 + row) * 512 + h * 64 + n0 + (lane & 15)] = t;
        }
    }
}

// ---------------- K_G: out = oh @ W_out + b_out; 8 LDS rows, 2 cols/thread ----------------
__global__ __launch_bounds__(256) void k_out(const float* __restrict__ oh,
                                             const float* __restrict__ Wout,
                                             const float* __restrict__ bout,
                                             float* __restrict__ out) {
    __shared__ float xs[8 * 512];            // 16 KB
    int tid = threadIdx.x;
    int i0 = blockIdx.x * 8;                 // 256 blocks
    const float4* xg = (const float4*)(oh + i0 * 512);
    float4* xs4 = (float4*)xs;
    #pragma unroll
    for (int j = 0; j < 4; ++j) xs4[j * 256 + tid] = xg[j * 256 + tid];
    __syncthreads();

    int col = tid;                           // cols col, col+256
    float a0[8], a1[8];
    #pragma unroll
    for (int r = 0; r < 8; ++r) { a0[r] = 0.f; a1[r] = 0.f; }
    const float* wp = Wout + col;
    for (int c4 = 0; c4 < 128; ++c4) {
        float w00 = wp[(c4 * 4 + 0) * 512];
        float w01 = wp[(c4 * 4 + 1) * 512];
        float w02 = wp[(c4 * 4 + 2) * 512];
        float w03 = wp[(c4 * 4 + 3) * 512];
        float w10 = wp[(c4 * 4 + 0) * 512 + 256];
        float w11 = wp[(c4 * 4 + 1) * 512 + 256];
        float w12 = wp[(c4 * 4 + 2) * 512 + 256];
        float w13 = wp[(c4 * 4 + 3) * 512 + 256];
        #pragma unroll
        for (int r = 0; r < 8; ++r) {
            float4 xv = *(const float4*)(xs + r * 512 + c4 * 4);
            a0[r] = fmaf(xv.x, w00, fmaf(xv.y, w01, fmaf(xv.z, w02, fmaf(xv.w, w03, a0[r]))));
            a1[r] = fmaf(xv.x, w10, fmaf(xv.y, w11, fmaf(xv.z, w12, fmaf(xv.w, w13, a1[r]))));
        }
    }
    float bias0 = bout[col], bias1 = bout[col + 256];
    #pragma unroll
    for (int r = 0; r < 8; ++r) {
        out[(i0 + r) * 512 + col]       = a0[r] + bias0;
        out[(i0 + r) * 512 + col + 256] = a1[r] + bias1;
    }
}

extern "C" void kernel_launch(void* const* d_in, const int* in_sizes, int n_in,
                              void* d_out, int out_size, void* d_ws, size_t ws_size,
                              hipStream_t stream) {
    const float* x     = (const float*)d_in[0];
    const float* Wqkv  = (const float*)d_in[1];
    const float* theta = (const float*)d_in[2];
    const float* Wout  = (const float*)d_in[3];
    const float* bout  = (const float*)d_in[4];

    float* out  = (float*)d_out;                  // [2,1024,512]
    float* attn = out + 2 * 1024 * 512;           // [2,8,1024,1024]

    float* ws  = (float*)d_ws;
    float* Wqp = ws;                               // 32768
    float* Wkp = ws + 32768;                       // 32768
    float* qp  = ws + 65536;                       // 131072
    float* kp  = ws + 196608;                      // 131072
    unsigned short* vThi = (unsigned short*)(ws + 327680);   // 1,048,576 u16
    unsigned short* vTlo = (unsigned short*)(ws + 851968);   // 1,048,576 u16
    float* oh  = ws + 1376256;                     // 1048576

    k_wproj   <<<128,  256, 0, stream>>>(Wqkv, theta, Wqp, Wkp);
    k_qkp     <<<512,  256, 0, stream>>>(x, Wqp, Wkp, qp, kp);
    k_vproj   <<<256,  256, 0, stream>>>(x, Wqkv, vThi, vTlo);
    k_attn_pv <<<2048, 256, 0, stream>>>(qp, kp, vThi, vTlo, attn, oh);
    k_out     <<<256,  256, 0, stream>>>(oh, Wout, bout, out);
}

// Round 8
// 169.361 us; speedup vs baseline: 1.1045x; 1.1045x over previous
//
#include <hip/hip_runtime.h>
#include <hip/hip_bf16.h>

// Sizes (fixed): b=2, n=1024, dim=512, h=8, L=8, dh=64
// exp(-d2/T) with T=0.1 -> exp2(C*d2), C = -10*log2(e)
#define CEXP (-14.4269504088896340736f)

typedef __attribute__((ext_vector_type(8))) short bfrag8;   // 8 bf16 (4 VGPR) MFMA operand
typedef __attribute__((ext_vector_type(4))) float fvec4;    // MFMA accumulator
typedef __attribute__((ext_vector_type(8))) unsigned short ushort8;

__device__ inline unsigned short f2bf(float f) {            // RNE float->bf16
    unsigned u = __builtin_bit_cast(unsigned, f);
    u += 0x7fffu + ((u >> 16) & 1u);
    return (unsigned short)(u >> 16);
}
__device__ inline float bf2f(unsigned short h) {
    unsigned u = ((unsigned)h) << 16;
    return __builtin_bit_cast(float, u);
}

// Wave64 sum via DPP (rocPRIM pattern). ctrl/rmask must be immediates -> template params.
template <int CTRL, int RMASK>
__device__ __forceinline__ float dpp_add(float v) {
    int m = __builtin_amdgcn_update_dpp(0, __builtin_bit_cast(int, v), CTRL, RMASK, 0xf, true);
    return v + __builtin_bit_cast(float, m);
}
__device__ __forceinline__ float wave_sum64(float v) {
    v = dpp_add<0xB1,  0xf>(v);   // quad_perm(1,0,3,2)
    v = dpp_add<0x4E,  0xf>(v);   // quad_perm(2,3,0,1)
    v = dpp_add<0x141, 0xf>(v);   // row_half_mirror
    v = dpp_add<0x140, 0xf>(v);   // row_mirror -> each row-of-16 has its sum
    v = dpp_add<0x142, 0xa>(v);   // row_bcast15 into rows 1,3
    v = dpp_add<0x143, 0xc>(v);   // row_bcast31 into rows 2,3
    return __builtin_bit_cast(float, __builtin_amdgcn_readlane(__builtin_bit_cast(int, v), 63));
}

// ---------------- K_B: Wqp[c][hl] = sum_d Wq[c][h*64+d]*th_hat[h][l][d]; also extract Wv ----
__global__ __launch_bounds__(256) void k_wproj(const float* __restrict__ Wqkv,
                                               const float* __restrict__ theta,
                                               float* __restrict__ Wqp,
                                               float* __restrict__ Wkp,
                                               float* __restrict__ Wv) {
    __shared__ float th_s[64 * 65];
    int tid = threadIdx.x;
    int hl = tid & 63, cl = tid >> 6;
    #pragma unroll
    for (int i = 0; i < 16; ++i) {
        int r = cl * 16 + i;
        th_s[r * 65 + hl] = theta[r * 64 + hl];
    }
    __syncthreads();
    const float* ts = th_s + hl * 65;
    float ss = 0.f;
    #pragma unroll 8
    for (int d = 0; d < 64; ++d) ss = fmaf(ts[d], ts[d], ss);
    float inv = rsqrtf(ss);
    int c = blockIdx.x * 4 + cl;
    int h = hl >> 3;
    const float* wq = Wqkv + c * 1536 + h * 64;
    const float* wk = wq + 512;
    float aq = 0.f, ak = 0.f;
    #pragma unroll 4
    for (int d = 0; d < 64; ++d) {
        float tv = ts[d];
        aq = fmaf(wq[d], tv, aq);
        ak = fmaf(wk[d], tv, ak);
    }
    Wqp[c * 64 + hl] = aq * inv;
    Wkp[c * 64 + hl] = ak * inv;

    // extract Wv[c][o] = Wqkv[c][1024+o] into contiguous [512][512] (per block: 4 rows)
    int c0 = blockIdx.x * 4;
    const float4* src = (const float4*)(Wqkv + 1024);
    float4* dst = (float4*)Wv;
    #pragma unroll
    for (int j = 0; j < 2; ++j) {
        int idx = j * 256 + tid;             // 512 float4 per block = 4 rows x 128
        int cr = c0 + (idx >> 7), o4 = idx & 127;
        dst[cr * 128 + o4] = src[cr * 384 + o4];
    }
}

// ---------------- K_C: qp/kp = scale * x @ W{q,k}p, layout [bh][l][n] ----------------
__global__ __launch_bounds__(256) void k_qkp(const float* __restrict__ x,
                                             const float* __restrict__ Wqp,
                                             const float* __restrict__ Wkp,
                                             float* __restrict__ qp,
                                             float* __restrict__ kp) {
    __shared__ float xs[4 * 512];            // 8 KB
    int tid = threadIdx.x;
    int i0 = blockIdx.x * 4;                 // 512 blocks
    const float4* xg = (const float4*)(x + i0 * 512);
    float4* xs4 = (float4*)xs;
    #pragma unroll
    for (int j = 0; j < 2; ++j) xs4[j * 256 + tid] = xg[j * 256 + tid];
    __syncthreads();

    int t  = tid & 127;
    int rg = tid >> 7;                       // 0/1 -> rows rg*2, rg*2+1
    int hl = t & 63;
    const float* Bm = (t & 64) ? Wkp : Wqp;
    const float* xr = xs + rg * 2 * 512;
    float a[2] = {0.f, 0.f};
    for (int c4 = 0; c4 < 128; ++c4) {
        float b0 = Bm[(c4 * 4 + 0) * 64 + hl];
        float b1 = Bm[(c4 * 4 + 1) * 64 + hl];
        float b2 = Bm[(c4 * 4 + 2) * 64 + hl];
        float b3 = Bm[(c4 * 4 + 3) * 64 + hl];
        #pragma unroll
        for (int r = 0; r < 2; ++r) {
            float4 xv = *(const float4*)(xr + r * 512 + c4 * 4);
            a[r] = fmaf(xv.x, b0, fmaf(xv.y, b1, fmaf(xv.z, b2, fmaf(xv.w, b3, a[r]))));
        }
    }
    int h = hl >> 3, l = hl & 7;
    float* dst = (t & 64) ? kp : qp;
    #pragma unroll
    for (int r = 0; r < 2; ++r) {
        int row = i0 + rg * 2 + r;
        int b = row >> 10, i = row & 1023;
        dst[((b * 8 + h) * 8 + l) * 1024 + i] = a[r] * 0.125f;
    }
}

// ---------------- K_D1: vnat = x @ Wv, natural layout [b n][h d] f32 (k_out clone) ------
__global__ __launch_bounds__(256) void k_vproj_nat(const float* __restrict__ x,
                                                   const float* __restrict__ Wv,
                                                   float* __restrict__ vnat) {
    __shared__ float xs[8 * 512];            // 16 KB
    int tid = threadIdx.x;
    int i0 = blockIdx.x * 8;                 // 256 blocks
    const float4* xg = (const float4*)(x + i0 * 512);
    float4* xs4 = (float4*)xs;
    #pragma unroll
    for (int j = 0; j < 4; ++j) xs4[j * 256 + tid] = xg[j * 256 + tid];
    __syncthreads();

    int col = tid;                           // cols col, col+256
    float a0[8], a1[8];
    #pragma unroll
    for (int r = 0; r < 8; ++r) { a0[r] = 0.f; a1[r] = 0.f; }
    const float* wp = Wv + col;
    for (int c4 = 0; c4 < 128; ++c4) {
        float w00 = wp[(c4 * 4 + 0) * 512];
        float w01 = wp[(c4 * 4 + 1) * 512];
        float w02 = wp[(c4 * 4 + 2) * 512];
        float w03 = wp[(c4 * 4 + 3) * 512];
        float w10 = wp[(c4 * 4 + 0) * 512 + 256];
        float w11 = wp[(c4 * 4 + 1) * 512 + 256];
        float w12 = wp[(c4 * 4 + 2) * 512 + 256];
        float w13 = wp[(c4 * 4 + 3) * 512 + 256];
        #pragma unroll
        for (int r = 0; r < 8; ++r) {
            float4 xv = *(const float4*)(xs + r * 512 + c4 * 4);
            a0[r] = fmaf(xv.x, w00, fmaf(xv.y, w01, fmaf(xv.z, w02, fmaf(xv.w, w03, a0[r]))));
            a1[r] = fmaf(xv.x, w10, fmaf(xv.y, w11, fmaf(xv.z, w12, fmaf(xv.w, w13, a1[r]))));
        }
    }
    #pragma unroll
    for (int r = 0; r < 8; ++r) {
        vnat[(i0 + r) * 512 + col]       = a0[r];
        vnat[(i0 + r) * 512 + col + 256] = a1[r];
    }
}

// ---------------- K_D2: vT = transpose(vnat) as bf16 hi/lo, [bh][d][n] ----------------
// per block: one (bh, 64-row tile); LDS 64x65 f32; both global sides coalesced.
__global__ __launch_bounds__(256) void k_vT(const float* __restrict__ vnat,
                                            unsigned short* __restrict__ vThi,
                                            unsigned short* __restrict__ vTlo) {
    __shared__ float ts[64 * 65];
    int blk = blockIdx.x;                    // 256 = 16 bh * 16 row-tiles
    int bh = blk >> 4;
    int i0 = (blk & 15) * 64;
    int b = bh >> 3, h = bh & 7;
    int tid = threadIdx.x;
    int col = tid & 63, r0 = tid >> 6;       // col = d-sub, 4 rows/pass
    const float* src = vnat + (size_t)(b * 1024 + i0) * 512 + h * 64;
    #pragma unroll
    for (int k = 0; k < 16; ++k) {
        int r = r0 + 4 * k;
        ts[r * 65 + col] = src[r * 512 + col];
    }
    __syncthreads();
    int i = tid & 63, d0 = tid >> 6;
    size_t base = (size_t)bh * 65536 + i0 + i;
    #pragma unroll
    for (int k = 0; k < 16; ++k) {
        int d = d0 + 4 * k;
        float val = ts[i * 65 + d];
        unsigned short hi = f2bf(val);
        vThi[base + (size_t)d * 1024] = hi;
        vTlo[base + (size_t)d * 1024] = f2bf(val - bf2f(hi));
    }
}

// ---------------- K_E: fused attention rows + MFMA PV ----------------
// Phase 1: softmax-average rows in regs. Stash P (bf16 hi/lo) to LDS. THEN issue attn
// stores (no barrier behind them -> they drain under phase-2 MFMA). Phase 2: oh = P @ v.
__global__ __launch_bounds__(256) void k_attn_pv(const float* __restrict__ qp,
                                                 const float* __restrict__ kp,
                                                 const unsigned short* __restrict__ vThi,
                                                 const unsigned short* __restrict__ vTlo,
                                                 float* __restrict__ attn,
                                                 float* __restrict__ oh) {
    __shared__ float s_buf[8 * 1024];        // 32 KB: kp (f32) phase 1; P hi/lo (bf16 [16][1024]) phase 2
    int bx = blockIdx.x;                     // 2048
    int bh = bx >> 7;
    int rowbase = (bx & 127) * 8;
    int tid = threadIdx.x;
    int w = tid >> 6, lane = tid & 63;

    const float4* kp4 = (const float4*)(kp + bh * 8192);
    float4* kps4 = (float4*)s_buf;
    #pragma unroll
    for (int k = 0; k < 8; ++k) kps4[k * 256 + tid] = kp4[k * 256 + tid];

    int rA = rowbase + 2 * w;
    int rB = rA + 1;
    float qA[8], qB[8];
    #pragma unroll
    for (int l = 0; l < 8; ++l) {
        qA[l] = qp[bh * 8192 + l * 1024 + rA];
        qB[l] = qp[bh * 8192 + l * 1024 + rB];
    }
    __syncthreads();

    float accA[16], accB[16];
    #pragma unroll
    for (int m = 0; m < 16; ++m) { accA[m] = 0.f; accB[m] = 0.f; }

    for (int l = 0; l < 8; ++l) {
        float kv[16], kv2[16];
        #pragma unroll
        for (int m = 0; m < 16; ++m) {
            kv[m] = s_buf[l * 1024 + m * 64 + lane];
            kv2[m] = CEXP * kv[m] * kv[m];       // C*k^2
        }
        float e[16];
        // ---- row A ----
        {
            float sq = -2.f * CEXP * qA[l];
            #pragma unroll
            for (int m = 0; m < 16; ++m) e[m] = __builtin_amdgcn_exp2f(fmaf(sq, kv[m], kv2[m]));
            float s = (((e[0]+e[1])+(e[2]+e[3])) + ((e[4]+e[5])+(e[6]+e[7])))
                    + (((e[8]+e[9])+(e[10]+e[11])) + ((e[12]+e[13])+(e[14]+e[15])));
            float inv = 0.125f * __builtin_amdgcn_rcpf(wave_sum64(s));
            #pragma unroll
            for (int m = 0; m < 16; ++m) accA[m] = fmaf(e[m], inv, accA[m]);
        }
        // ---- row B ----
        {
            float sq = -2.f * CEXP * qB[l];
            #pragma unroll
            for (int m = 0; m < 16; ++m) e[m] = __builtin_amdgcn_exp2f(fmaf(sq, kv[m], kv2[m]));
            float s = (((e[0]+e[1])+(e[2]+e[3])) + ((e[4]+e[5])+(e[6]+e[7])))
                    + (((e[8]+e[9])+(e[10]+e[11])) + ((e[12]+e[13])+(e[14]+e[15])));
            float inv = 0.125f * __builtin_amdgcn_rcpf(wave_sum64(s));
            #pragma unroll
            for (int m = 0; m < 16; ++m) accB[m] = fmaf(e[m], inv, accB[m]);
        }
    }

    __syncthreads();   // all waves done reading kp from s_buf

    // stash P as bf16 hi (rows 0-7) / lo (rows 8-15), XOR-swizzled: idx = r*1024 + (j ^ ((r&7)<<3))
    unsigned short* ps = (unsigned short*)s_buf;
    int lrA = 2 * w, lrB = lrA + 1;
    int swzA = lrA << 3, swzB = lrB << 3;
    #pragma unroll
    for (int m = 0; m < 16; ++m) {
        int j = m * 64 + lane;
        unsigned short hA = f2bf(accA[m]);
        unsigned short hB = f2bf(accB[m]);
        ps[lrA * 1024 + (j ^ swzA)]       = hA;
        ps[lrB * 1024 + (j ^ swzB)]       = hB;
        ps[(lrA + 8) * 1024 + (j ^ swzA)] = f2bf(accA[m] - bf2f(hA));
        ps[(lrB + 8) * 1024 + (j ^ swzB)] = f2bf(accB[m] - bf2f(hB));
    }
    __syncthreads();

    // attn stores AFTER the last barrier: fire-and-forget, drain under phase-2 compute.
    float* aA = attn + ((size_t)(bh * 1024 + rA)) * 1024 + lane;
    float* aB = attn + ((size_t)(bh * 1024 + rB)) * 1024 + lane;
    #pragma unroll
    for (int m = 0; m < 16; ++m) {
        __builtin_nontemporal_store(accA[m], aA + m * 64);
        __builtin_nontemporal_store(accB[m], aB + m * 64);
    }

    // Phase 2: wave w computes oh cols n0..n0+15 over full K=1024 via mfma 16x16x32.
    int n0 = w * 16;
    int ar  = lane & 15;
    int asw = (ar & 7) << 3;
    int ak  = (lane >> 4) * 8;
    const unsigned short* ap = ps + ar * 1024;
    size_t boff = (size_t)bh * 65536 + (size_t)(n0 + (lane & 15)) * 1024 + ak;
    const unsigned short* bh_p = vThi + boff;
    const unsigned short* bl_p = vTlo + boff;
    fvec4 acc = {0.f, 0.f, 0.f, 0.f};
    #pragma unroll 4
    for (int s = 0; s < 32; ++s) {
        bfrag8 a  = *(const bfrag8*)(ap + ((s * 32 + ak) ^ asw));
        bfrag8 vh = *(const bfrag8*)(bh_p + s * 32);
        bfrag8 vl = *(const bfrag8*)(bl_p + s * 32);
        acc = __builtin_amdgcn_mfma_f32_16x16x32_bf16(a, vh, acc, 0, 0, 0);
        acc = __builtin_amdgcn_mfma_f32_16x16x32_bf16(a, vl, acc, 0, 0, 0);
    }
    int b = bh >> 3, h = bh & 7;
    #pragma unroll
    for (int q = 0; q < 4; ++q) {
        float t = acc[q] + __shfl_xor(acc[q], 32);   // C[r] + C[r+8]
        if (lane < 32) {
            int row = rowbase + (lane >> 4) * 4 + q;
            oh[(b * 1024 + row) * 512 + h * 64 + n0 + (lane & 15)] = t;
        }
    }
}

// ---------------- K_G: out = oh @ W_out + b_out; 8 LDS rows, 2 cols/thread ----------------
__global__ __launch_bounds__(256) void k_out(const float* __restrict__ oh,
                                             const float* __restrict__ Wout,
                                             const float* __restrict__ bout,
                                             float* __restrict__ out) {
    __shared__ float xs[8 * 512];            // 16 KB
    int tid = threadIdx.x;
    int i0 = blockIdx.x * 8;                 // 256 blocks
    const float4* xg = (const float4*)(oh + i0 * 512);
    float4* xs4 = (float4*)xs;
    #pragma unroll
    for (int j = 0; j < 4; ++j) xs4[j * 256 + tid] = xg[j * 256 + tid];
    __syncthreads();

    int col = tid;                           // cols col, col+256
    float a0[8], a1[8];
    #pragma unroll
    for (int r = 0; r < 8; ++r) { a0[r] = 0.f; a1[r] = 0.f; }
    const float* wp = Wout + col;
    for (int c4 = 0; c4 < 128; ++c4) {
        float w00 = wp[(c4 * 4 + 0) * 512];
        float w01 = wp[(c4 * 4 + 1) * 512];
        float w02 = wp[(c4 * 4 + 2) * 512];
        float w03 = wp[(c4 * 4 + 3) * 512];
        float w10 = wp[(c4 * 4 + 0) * 512 + 256];
        float w11 = wp[(c4 * 4 + 1) * 512 + 256];
        float w12 = wp[(c4 * 4 + 2) * 512 + 256];
        float w13 = wp[(c4 * 4 + 3) * 512 + 256];
        #pragma unroll
        for (int r = 0; r < 8; ++r) {
            float4 xv = *(const float4*)(xs + r * 512 + c4 * 4);
            a0[r] = fmaf(xv.x, w00, fmaf(xv.y, w01, fmaf(xv.z, w02, fmaf(xv.w, w03, a0[r]))));
            a1[r] = fmaf(xv.x, w10, fmaf(xv.y, w11, fmaf(xv.z, w12, fmaf(xv.w, w13, a1[r]))));
        }
    }
    float bias0 = bout[col], bias1 = bout[col + 256];
    #pragma unroll
    for (int r = 0; r < 8; ++r) {
        out[(i0 + r) * 512 + col]       = a0[r] + bias0;
        out[(i0 + r) * 512 + col + 256] = a1[r] + bias1;
    }
}

extern "C" void kernel_launch(void* const* d_in, const int* in_sizes, int n_in,
                              void* d_out, int out_size, void* d_ws, size_t ws_size,
                              hipStream_t stream) {
    const float* x     = (const float*)d_in[0];
    const float* Wqkv  = (const float*)d_in[1];
    const float* theta = (const float*)d_in[2];
    const float* Wout  = (const float*)d_in[3];
    const float* bout  = (const float*)d_in[4];

    float* out  = (float*)d_out;                  // [2,1024,512]
    float* attn = out + 2 * 1024 * 512;           // [2,8,1024,1024]

    float* ws  = (float*)d_ws;
    float* Wqp = ws;                               // 32768
    float* Wkp = ws + 32768;                       // 32768
    float* qp  = ws + 65536;                       // 131072
    float* kp  = ws + 196608;                      // 131072
    unsigned short* vThi = (unsigned short*)(ws + 327680);   // 1,048,576 u16
    unsigned short* vTlo = (unsigned short*)(ws + 851968);   // 1,048,576 u16
    float* vnat = ws + 1376256;                    // 1048576 (aliases oh; vnat dead before attn writes oh)
    float* oh   = ws + 1376256;
    float* Wv   = ws + 2424832;                    // 262144

    k_wproj     <<<128,  256, 0, stream>>>(Wqkv, theta, Wqp, Wkp, Wv);
    k_qkp       <<<512,  256, 0, stream>>>(x, Wqp, Wkp, qp, kp);
    k_vproj_nat <<<256,  256, 0, stream>>>(x, Wv, vnat);
    k_vT        <<<256,  256, 0, stream>>>(vnat, vThi, vTlo);
    k_attn_pv   <<<2048, 256, 0, stream>>>(qp, kp, vThi, vTlo, attn, oh);
    k_out       <<<256,  256, 0, stream>>>(oh, Wout, bout, out);
}

// Round 9
// 164.422 us; speedup vs baseline: 1.1377x; 1.0300x over previous
//
#include <hip/hip_runtime.h>
#include <hip/hip_bf16.h>

// Sizes (fixed): b=2, n=1024, dim=512, h=8, L=8, dh=64
// exp(-d2/T) with T=0.1 -> exp2(C*d2), C = -10*log2(e)
#define CEXP (-14.4269504088896340736f)

typedef __attribute__((ext_vector_type(8))) short bfrag8;   // 8 bf16 (4 VGPR) MFMA operand
typedef __attribute__((ext_vector_type(4))) float fvec4;    // MFMA accumulator
typedef __attribute__((ext_vector_type(8))) unsigned short ushort8;

__device__ inline unsigned short f2bf(float f) {            // RNE float->bf16
    unsigned u = __builtin_bit_cast(unsigned, f);
    u += 0x7fffu + ((u >> 16) & 1u);
    return (unsigned short)(u >> 16);
}
__device__ inline float bf2f(unsigned short h) {
    unsigned u = ((unsigned)h) << 16;
    return __builtin_bit_cast(float, u);
}

// Wave64 sum via DPP (rocPRIM pattern). ctrl/rmask must be immediates -> template params.
template <int CTRL, int RMASK>
__device__ __forceinline__ float dpp_add(float v) {
    int m = __builtin_amdgcn_update_dpp(0, __builtin_bit_cast(int, v), CTRL, RMASK, 0xf, true);
    return v + __builtin_bit_cast(float, m);
}
__device__ __forceinline__ float wave_sum64(float v) {
    v = dpp_add<0xB1,  0xf>(v);   // quad_perm(1,0,3,2)
    v = dpp_add<0x4E,  0xf>(v);   // quad_perm(2,3,0,1)
    v = dpp_add<0x141, 0xf>(v);   // row_half_mirror
    v = dpp_add<0x140, 0xf>(v);   // row_mirror -> each row-of-16 has its sum
    v = dpp_add<0x142, 0xa>(v);   // row_bcast15 into rows 1,3
    v = dpp_add<0x143, 0xc>(v);   // row_bcast31 into rows 2,3
    return __builtin_bit_cast(float, __builtin_amdgcn_readlane(__builtin_bit_cast(int, v), 63));
}

// ---------------- K_B: Wqp[c][hl] = sum_d Wq[c][h*64+d]*th_hat[h][l][d]; also extract Wv ----
__global__ __launch_bounds__(256) void k_wproj(const float* __restrict__ Wqkv,
                                               const float* __restrict__ theta,
                                               float* __restrict__ Wqp,
                                               float* __restrict__ Wkp,
                                               float* __restrict__ Wv) {
    __shared__ float th_s[64 * 65];
    int tid = threadIdx.x;
    int hl = tid & 63, cl = tid >> 6;
    #pragma unroll
    for (int i = 0; i < 16; ++i) {
        int r = cl * 16 + i;
        th_s[r * 65 + hl] = theta[r * 64 + hl];
    }
    __syncthreads();
    const float* ts = th_s + hl * 65;
    float ss = 0.f;
    #pragma unroll 8
    for (int d = 0; d < 64; ++d) ss = fmaf(ts[d], ts[d], ss);
    float inv = rsqrtf(ss);
    int c = blockIdx.x * 4 + cl;
    int h = hl >> 3;
    const float* wq = Wqkv + c * 1536 + h * 64;
    const float* wk = wq + 512;
    float aq = 0.f, ak = 0.f;
    #pragma unroll 4
    for (int d = 0; d < 64; ++d) {
        float tv = ts[d];
        aq = fmaf(wq[d], tv, aq);
        ak = fmaf(wk[d], tv, ak);
    }
    Wqp[c * 64 + hl] = aq * inv;
    Wkp[c * 64 + hl] = ak * inv;

    // extract Wv[c][o] = Wqkv[c][1024+o] into contiguous [512][512] (per block: 4 rows)
    int c0 = blockIdx.x * 4;
    const float4* src = (const float4*)(Wqkv + 1024);
    float4* dst = (float4*)Wv;
    #pragma unroll
    for (int j = 0; j < 2; ++j) {
        int idx = j * 256 + tid;             // 512 float4 per block = 4 rows x 128
        int cr = c0 + (idx >> 7), o4 = idx & 127;
        dst[cr * 128 + o4] = src[cr * 384 + o4];
    }
}

// ---------------- K_C: qp/kp = scale * x @ W{q,k}p, layout [bh][l][n] ----------------
__global__ __launch_bounds__(256) void k_qkp(const float* __restrict__ x,
                                             const float* __restrict__ Wqp,
                                             const float* __restrict__ Wkp,
                                             float* __restrict__ qp,
                                             float* __restrict__ kp) {
    __shared__ float xs[4 * 512];            // 8 KB
    int tid = threadIdx.x;
    int i0 = blockIdx.x * 4;                 // 512 blocks
    const float4* xg = (const float4*)(x + i0 * 512);
    float4* xs4 = (float4*)xs;
    #pragma unroll
    for (int j = 0; j < 2; ++j) xs4[j * 256 + tid] = xg[j * 256 + tid];
    __syncthreads();

    int t  = tid & 127;
    int rg = tid >> 7;                       // 0/1 -> rows rg*2, rg*2+1
    int hl = t & 63;
    const float* Bm = (t & 64) ? Wkp : Wqp;
    const float* xr = xs + rg * 2 * 512;
    float a[2] = {0.f, 0.f};
    for (int c4 = 0; c4 < 128; ++c4) {
        float b0 = Bm[(c4 * 4 + 0) * 64 + hl];
        float b1 = Bm[(c4 * 4 + 1) * 64 + hl];
        float b2 = Bm[(c4 * 4 + 2) * 64 + hl];
        float b3 = Bm[(c4 * 4 + 3) * 64 + hl];
        #pragma unroll
        for (int r = 0; r < 2; ++r) {
            float4 xv = *(const float4*)(xr + r * 512 + c4 * 4);
            a[r] = fmaf(xv.x, b0, fmaf(xv.y, b1, fmaf(xv.z, b2, fmaf(xv.w, b3, a[r]))));
        }
    }
    int h = hl >> 3, l = hl & 7;
    float* dst = (t & 64) ? kp : qp;
    #pragma unroll
    for (int r = 0; r < 2; ++r) {
        int row = i0 + rg * 2 + r;
        int b = row >> 10, i = row & 1023;
        dst[((b * 8 + h) * 8 + l) * 1024 + i] = a[r] * 0.125f;
    }
}

// ---------------- K_D1: vnat = x @ Wv, natural layout; 512 thr, 1 col x 8 rows ----------
__global__ __launch_bounds__(512) void k_vproj_nat(const float* __restrict__ x,
                                                   const float* __restrict__ Wv,
                                                   float* __restrict__ vnat) {
    __shared__ float xs[8 * 512];            // 16 KB
    int tid = threadIdx.x;                   // 512
    int i0 = blockIdx.x * 8;                 // 256 blocks
    const float4* xg = (const float4*)(x + i0 * 512);
    float4* xs4 = (float4*)xs;
    #pragma unroll
    for (int j = 0; j < 2; ++j) xs4[j * 512 + tid] = xg[j * 512 + tid];
    __syncthreads();

    int col = tid;
    float a[8];
    #pragma unroll
    for (int r = 0; r < 8; ++r) a[r] = 0.f;
    const float* wp = Wv + col;
    for (int c4 = 0; c4 < 128; ++c4) {
        float w0 = wp[(c4 * 4 + 0) * 512];
        float w1 = wp[(c4 * 4 + 1) * 512];
        float w2 = wp[(c4 * 4 + 2) * 512];
        float w3 = wp[(c4 * 4 + 3) * 512];
        #pragma unroll
        for (int r = 0; r < 8; ++r) {
            float4 xv = *(const float4*)(xs + r * 512 + c4 * 4);
            a[r] = fmaf(xv.x, w0, fmaf(xv.y, w1, fmaf(xv.z, w2, fmaf(xv.w, w3, a[r]))));
        }
    }
    #pragma unroll
    for (int r = 0; r < 8; ++r) vnat[(i0 + r) * 512 + col] = a[r];
}

// ---------------- K_D2: vT = transpose(vnat) as bf16 hi/lo, [bh][d][n] ----------------
__global__ __launch_bounds__(256) void k_vT(const float* __restrict__ vnat,
                                            unsigned short* __restrict__ vThi,
                                            unsigned short* __restrict__ vTlo) {
    __shared__ float ts[64 * 65];
    int blk = blockIdx.x;                    // 256 = 16 bh * 16 row-tiles
    int bh = blk >> 4;
    int i0 = (blk & 15) * 64;
    int b = bh >> 3, h = bh & 7;
    int tid = threadIdx.x;
    int col = tid & 63, r0 = tid >> 6;       // col = d-sub, 4 rows/pass
    const float* src = vnat + (size_t)(b * 1024 + i0) * 512 + h * 64;
    #pragma unroll
    for (int k = 0; k < 16; ++k) {
        int r = r0 + 4 * k;
        ts[r * 65 + col] = src[r * 512 + col];
    }
    __syncthreads();
    int i = tid & 63, d0 = tid >> 6;
    size_t base = (size_t)bh * 65536 + i0 + i;
    #pragma unroll
    for (int k = 0; k < 16; ++k) {
        int d = d0 + 4 * k;
        float val = ts[i * 65 + d];
        unsigned short hi = f2bf(val);
        vThi[base + (size_t)d * 1024] = hi;
        vTlo[base + (size_t)d * 1024] = f2bf(val - bf2f(hi));
    }
}

// ---------------- K_E: fused attention rows + MFMA PV; 512 thr / 8 waves ----------------
// Wave w owns row rowbase+w in phase 1. Phase 2: split-K across wave pairs (w, w+4).
__global__ __launch_bounds__(512) void k_attn_pv(const float* __restrict__ qp,
                                                 const float* __restrict__ kp,
                                                 const unsigned short* __restrict__ vThi,
                                                 const unsigned short* __restrict__ vTlo,
                                                 float* __restrict__ attn,
                                                 float* __restrict__ oh) {
    __shared__ float s_buf[8 * 1024];        // 32 KB: kp (f32) phase 1; P hi/lo bf16 [16][1024] phase 2
    __shared__ float sc[4 * 64 * 4];         // 4 KB split-K combine scratch
    int bx = blockIdx.x;                     // 2048
    int bh = bx >> 7;
    int rowbase = (bx & 127) * 8;
    int tid = threadIdx.x;
    int w = tid >> 6, lane = tid & 63;

    const float4* kp4 = (const float4*)(kp + bh * 8192);
    float4* kps4 = (float4*)s_buf;
    #pragma unroll
    for (int k = 0; k < 4; ++k) kps4[k * 512 + tid] = kp4[k * 512 + tid];

    int r = rowbase + w;
    float qv[8];
    #pragma unroll
    for (int l = 0; l < 8; ++l) qv[l] = qp[bh * 8192 + l * 1024 + r];
    __syncthreads();

    float acc[16];
    #pragma unroll
    for (int m = 0; m < 16; ++m) acc[m] = 0.f;

    for (int l = 0; l < 8; ++l) {
        float kv[16], kv2[16], e[16];
        #pragma unroll
        for (int m = 0; m < 16; ++m) {
            kv[m] = s_buf[l * 1024 + m * 64 + lane];
            kv2[m] = CEXP * kv[m] * kv[m];       // C*k^2
        }
        float sq = -2.f * CEXP * qv[l];
        #pragma unroll
        for (int m = 0; m < 16; ++m) e[m] = __builtin_amdgcn_exp2f(fmaf(sq, kv[m], kv2[m]));
        float s = (((e[0]+e[1])+(e[2]+e[3])) + ((e[4]+e[5])+(e[6]+e[7])))
                + (((e[8]+e[9])+(e[10]+e[11])) + ((e[12]+e[13])+(e[14]+e[15])));
        float inv = 0.125f * __builtin_amdgcn_rcpf(wave_sum64(s));
        #pragma unroll
        for (int m = 0; m < 16; ++m) acc[m] = fmaf(e[m], inv, acc[m]);
    }

    __syncthreads();   // all waves done reading kp from s_buf

    // stash P row w as bf16: hi -> row w, lo -> row w+8; XOR-swizzle j ^ (w<<3)
    unsigned short* ps = (unsigned short*)s_buf;
    int swz = w << 3;
    #pragma unroll
    for (int m = 0; m < 16; ++m) {
        int j = m * 64 + lane;
        unsigned short hi = f2bf(acc[m]);
        ps[w * 1024 + (j ^ swz)]       = hi;
        ps[(w + 8) * 1024 + (j ^ swz)] = f2bf(acc[m] - bf2f(hi));
    }
    __syncthreads();

    // attn stores: fire-and-forget, drain under phase-2 compute.
    float* aR = attn + ((size_t)(bh * 1024 + r)) * 1024 + lane;
    #pragma unroll
    for (int m = 0; m < 16; ++m) __builtin_nontemporal_store(acc[m], aR + m * 64);

    // Phase 2: wave w -> cols n0..n0+15, K-half kh; pairs (w, w+4) combine via LDS.
    int n0 = (w & 3) * 16;
    int kh = w >> 2;
    int ar  = lane & 15;
    int asw = (ar & 7) << 3;
    int ak  = (lane >> 4) * 8;
    const unsigned short* ap = ps + ar * 1024;
    size_t boff = (size_t)bh * 65536 + (size_t)(n0 + (lane & 15)) * 1024 + ak;
    const unsigned short* bh_p = vThi + boff;
    const unsigned short* bl_p = vTlo + boff;
    fvec4 c2 = {0.f, 0.f, 0.f, 0.f};
    #pragma unroll 4
    for (int s = kh * 16; s < kh * 16 + 16; ++s) {
        bfrag8 a  = *(const bfrag8*)(ap + ((s * 32 + ak) ^ asw));
        bfrag8 vh = *(const bfrag8*)(bh_p + s * 32);
        bfrag8 vl = *(const bfrag8*)(bl_p + s * 32);
        c2 = __builtin_amdgcn_mfma_f32_16x16x32_bf16(a, vh, c2, 0, 0, 0);
        c2 = __builtin_amdgcn_mfma_f32_16x16x32_bf16(a, vl, c2, 0, 0, 0);
    }
    if (w >= 4) {
        #pragma unroll
        for (int q = 0; q < 4; ++q) sc[(w - 4) * 256 + lane * 4 + q] = c2[q];
    }
    __syncthreads();
    if (w < 4) {
        int b = bh >> 3, h = bh & 7;
        #pragma unroll
        for (int q = 0; q < 4; ++q) {
            float t = c2[q] + sc[w * 256 + lane * 4 + q];
            t += __shfl_xor(t, 32);               // hi row + lo row
            if (lane < 32) {
                int row = rowbase + (lane >> 4) * 4 + q;
                oh[(b * 1024 + row) * 512 + h * 64 + n0 + (lane & 15)] = t;
            }
        }
    }
}

// ---------------- K_G: out = oh @ W_out + b_out; 512 thr, 1 col x 8 rows ----------------
__global__ __launch_bounds__(512) void k_out(const float* __restrict__ oh,
                                             const float* __restrict__ Wout,
                                             const float* __restrict__ bout,
                                             float* __restrict__ out) {
    __shared__ float xs[8 * 512];            // 16 KB
    int tid = threadIdx.x;                   // 512
    int i0 = blockIdx.x * 8;                 // 256 blocks
    const float4* xg = (const float4*)(oh + i0 * 512);
    float4* xs4 = (float4*)xs;
    #pragma unroll
    for (int j = 0; j < 2; ++j) xs4[j * 512 + tid] = xg[j * 512 + tid];
    __syncthreads();

    int col = tid;
    float a[8];
    #pragma unroll
    for (int r = 0; r < 8; ++r) a[r] = 0.f;
    const float* wp = Wout + col;
    for (int c4 = 0; c4 < 128; ++c4) {
        float w0 = wp[(c4 * 4 + 0) * 512];
        float w1 = wp[(c4 * 4 + 1) * 512];
        float w2 = wp[(c4 * 4 + 2) * 512];
        float w3 = wp[(c4 * 4 + 3) * 512];
        #pragma unroll
        for (int r = 0; r < 8; ++r) {
            float4 xv = *(const float4*)(xs + r * 512 + c4 * 4);
            a[r] = fmaf(xv.x, w0, fmaf(xv.y, w1, fmaf(xv.z, w2, fmaf(xv.w, w3, a[r]))));
        }
    }
    float bias = bout[col];
    #pragma unroll
    for (int r = 0; r < 8; ++r) out[(i0 + r) * 512 + col] = a[r] + bias;
}

extern "C" void kernel_launch(void* const* d_in, const int* in_sizes, int n_in,
                              void* d_out, int out_size, void* d_ws, size_t ws_size,
                              hipStream_t stream) {
    const float* x     = (const float*)d_in[0];
    const float* Wqkv  = (const float*)d_in[1];
    const float* theta = (const float*)d_in[2];
    const float* Wout  = (const float*)d_in[3];
    const float* bout  = (const float*)d_in[4];

    float* out  = (float*)d_out;                  // [2,1024,512]
    float* attn = out + 2 * 1024 * 512;           // [2,8,1024,1024]

    float* ws  = (float*)d_ws;
    float* Wqp = ws;                               // 32768
    float* Wkp = ws + 32768;                       // 32768
    float* qp  = ws + 65536;                       // 131072
    float* kp  = ws + 196608;                      // 131072
    unsigned short* vThi = (unsigned short*)(ws + 327680);   // 1,048,576 u16
    unsigned short* vTlo = (unsigned short*)(ws + 851968);   // 1,048,576 u16
    float* vnat = ws + 1376256;                    // 1048576 (aliases oh; vnat dead before attn writes oh)
    float* oh   = ws + 1376256;
    float* Wv   = ws + 2424832;                    // 262144

    k_wproj     <<<128,  256, 0, stream>>>(Wqkv, theta, Wqp, Wkp, Wv);
    k_qkp       <<<512,  256, 0, stream>>>(x, Wqp, Wkp, qp, kp);
    k_vproj_nat <<<256,  512, 0, stream>>>(x, Wv, vnat);
    k_vT        <<<256,  256, 0, stream>>>(vnat, vThi, vTlo);
    k_attn_pv   <<<2048, 512, 0, stream>>>(qp, kp, vThi, vTlo, attn, oh);
    k_out       <<<256,  512, 0, stream>>>(oh, Wout, bout, out);
}